// Round 1
// baseline (189.272 us; speedup 1.0000x reference)
//
#include <hip/hip_runtime.h>
#include <hip/hip_bf16.h>
#include <math.h>

// Problem constants
#define B_ROWS 8192
#define N_PTS  16384
#define D_DIM  256

// GEMM tiling
#define BM 128
#define BN 128
#define BK 32
#define KSTEPS (D_DIM / BK)     // 8
#define NSPLIT 8
#define CHUNK  (N_PTS / NSPLIT) // 2048
#define NTILES (CHUNK / BN)     // 16

// Folded constants
#define SCALE_F 144.26950408889634f   // 100 * log2(e)   (logits scaled to log2 domain)
#define LN2_F   0.6931471805599453f
#define LOG2E_F 1.4426950408889634f
#define GN_F    354.2135193f          // -(256/2) * ln(2*pi*0.01)

typedef __attribute__((ext_vector_type(8))) __bf16 bf16x8;
typedef __attribute__((ext_vector_type(4))) float  f32x4;

__device__ __forceinline__ float fexp2(float x) {
#if __has_builtin(__builtin_amdgcn_exp2f)
    return __builtin_amdgcn_exp2f(x);   // flush-to-zero below 2^-126 is exactly what LSE wants
#else
    return exp2f(x);
#endif
}

__device__ __forceinline__ void async_load16(const void* g, void* l) {
    __builtin_amdgcn_global_load_lds(
        (const __attribute__((address_space(1))) void*)g,
        (__attribute__((address_space(3))) void*)l,
        16, 0, 0);
}

// ---- prep: x -> bf16, row const rc[b] = GN - 50*||x_b||^2 ----
__global__ void prep_x_kernel(const float* __restrict__ x, __bf16* __restrict__ xb,
                              float* __restrict__ rc)
{
    const int b = blockIdx.x;
    const int d = threadIdx.x;
    float v = x[(size_t)b * D_DIM + d];
    xb[(size_t)b * D_DIM + d] = (__bf16)v;
    float sq = v * v;
    #pragma unroll
    for (int off = 32; off > 0; off >>= 1) sq += __shfl_down(sq, off);
    __shared__ float red[4];
    if ((d & 63) == 0) red[d >> 6] = sq;
    __syncthreads();
    if (d == 0) rc[b] = GN_F - 50.0f * (red[0] + red[1] + red[2] + red[3]);
}

// ---- prep: X -> bf16, col const c2[n] = (W[n] - 50*||X_n||^2)*log2e ----
__global__ void prep_X_kernel(const float* __restrict__ X, const float* __restrict__ W,
                              __bf16* __restrict__ Xb, float* __restrict__ c2)
{
    const int n = blockIdx.x;
    const int d = threadIdx.x;
    float v = X[(size_t)n * D_DIM + d];
    Xb[(size_t)n * D_DIM + d] = (__bf16)v;
    float sq = v * v;
    #pragma unroll
    for (int off = 32; off > 0; off >>= 1) sq += __shfl_down(sq, off);
    __shared__ float red[4];
    if ((d & 63) == 0) red[d >> 6] = sq;
    __syncthreads();
    if (d == 0)
        c2[n] = (W[n] - 50.0f * (red[0] + red[1] + red[2] + red[3])) * LOG2E_F;
}

// ---- prep: lseW = logsumexp(W) (natural log) ----
__global__ void prep_w_kernel(const float* __restrict__ W, float* __restrict__ lsew)
{
    __shared__ float sm[256];
    const int t = threadIdx.x;
    float mx = -INFINITY;
    for (int i = t; i < N_PTS; i += 256) mx = fmaxf(mx, W[i]);
    sm[t] = mx; __syncthreads();
    for (int s = 128; s > 0; s >>= 1) { if (t < s) sm[t] = fmaxf(sm[t], sm[t + s]); __syncthreads(); }
    float M = sm[0]; __syncthreads();
    float acc = 0.f;
    for (int i = t; i < N_PTS; i += 256) acc += __expf(W[i] - M);
    sm[t] = acc; __syncthreads();
    for (int s = 128; s > 0; s >>= 1) { if (t < s) sm[t] += sm[t + s]; __syncthreads(); }
    if (t == 0) lsew[0] = M + __logf(sm[0]);
}

// ---- main: fused bf16 MFMA GEMM + online log2-sum-exp over n-chunk ----
__global__ __launch_bounds__(256, 2) void kde_gemm(
    const __bf16* __restrict__ xb, const __bf16* __restrict__ Xb,
    const float* __restrict__ c2, float* __restrict__ pm, float* __restrict__ ps)
{
    __shared__ __align__(16) __bf16 As[BM * BK];   // 8 KB
    __shared__ __align__(16) __bf16 Bs[BN * BK];   // 8 KB
    __shared__ float redM[2][BM];
    __shared__ float redS[2][BM];

    const int tid  = threadIdx.x;
    const int lane = tid & 63;
    const int w    = tid >> 6;
    const int wy   = w >> 1;
    const int wx   = w & 1;
    const int l15  = lane & 15;
    const int quad = lane >> 4;

    const int b0    = blockIdx.x * BM;
    const int chunk = blockIdx.y;
    const int nbase = chunk * CHUNK;

    // per-lane online LSE state: rows = wy*64 + i*16 + quad*4 + r, cols owned by this lane
    float m_[4][4], s_[4][4];
    #pragma unroll
    for (int i = 0; i < 4; ++i)
        #pragma unroll
        for (int r = 0; r < 4; ++r) { m_[i][r] = -INFINITY; s_[i][r] = 0.0f; }

    // staging pattern: idx = q*256 + tid; row = idx>>2 (64B per row), kc = idx&3 (16B units)
    const int row0 = tid >> 2,          kc0 = tid & 3;
    const int row1 = (256 + tid) >> 2,  kc1 = tid & 3;
    const int ldsbase0 = (w * 64) * 8;          // elements; wave-uniform
    const int ldsbase1 = (256 + w * 64) * 8;

    const __bf16* xrow0 = xb + (size_t)(b0 + row0) * D_DIM + kc0 * 8;
    const __bf16* xrow1 = xb + (size_t)(b0 + row1) * D_DIM + kc1 * 8;

    for (int nt = 0; nt < NTILES; ++nt) {
        const int n0 = nbase + nt * BN;

        float c2v[4];
        #pragma unroll
        for (int j = 0; j < 4; ++j)
            c2v[j] = c2[n0 + wx * 64 + j * 16 + l15];

        f32x4 acc[4][4];
        #pragma unroll
        for (int i = 0; i < 4; ++i)
            #pragma unroll
            for (int j = 0; j < 4; ++j) {
                f32x4 z = {0.f, 0.f, 0.f, 0.f};
                acc[i][j] = z;
            }

        const __bf16* Xrow0 = Xb + (size_t)(n0 + row0) * D_DIM + kc0 * 8;
        const __bf16* Xrow1 = Xb + (size_t)(n0 + row1) * D_DIM + kc1 * 8;

        #pragma unroll
        for (int kt = 0; kt < KSTEPS; ++kt) {
            const int ko = kt * BK;
            async_load16(xrow0 + ko, &As[ldsbase0]);
            async_load16(xrow1 + ko, &As[ldsbase1]);
            async_load16(Xrow0 + ko, &Bs[ldsbase0]);
            async_load16(Xrow1 + ko, &Bs[ldsbase1]);
            __syncthreads();   // drains vmcnt -> tiles visible

            bf16x8 af[4], bfr[4];
            #pragma unroll
            for (int i = 0; i < 4; ++i)
                af[i] = *(const bf16x8*)&As[(wy * 64 + i * 16 + l15) * BK + quad * 8];
            #pragma unroll
            for (int j = 0; j < 4; ++j)
                bfr[j] = *(const bf16x8*)&Bs[(wx * 64 + j * 16 + l15) * BK + quad * 8];
            #pragma unroll
            for (int i = 0; i < 4; ++i)
                #pragma unroll
                for (int j = 0; j < 4; ++j)
                    acc[i][j] = __builtin_amdgcn_mfma_f32_16x16x32_bf16(af[i], bfr[j], acc[i][j], 0, 0, 0);
            __syncthreads();   // before next k-step overwrites LDS
        }

        // fused epilogue: online LSE (log2 domain), purely per-lane
        #pragma unroll
        for (int i = 0; i < 4; ++i) {
            #pragma unroll
            for (int r = 0; r < 4; ++r) {
                float v0 = fmaf(SCALE_F, acc[i][0][r], c2v[0]);
                float v1 = fmaf(SCALE_F, acc[i][1][r], c2v[1]);
                float v2 = fmaf(SCALE_F, acc[i][2][r], c2v[2]);
                float v3 = fmaf(SCALE_F, acc[i][3][r], c2v[3]);
                float tm = fmaxf(fmaxf(v0, v1), fmaxf(v2, v3));
                float om = m_[i][r];
                float nm = fmaxf(om, tm);
                float e  = fexp2(v0 - nm) + fexp2(v1 - nm) + fexp2(v2 - nm) + fexp2(v3 - nm);
                s_[i][r] = fmaf(s_[i][r], fexp2(om - nm), e);
                m_[i][r] = nm;
            }
        }
    }

    // reduce (m,s) across the 16 lanes sharing each row, then across wx waves
    #pragma unroll
    for (int i = 0; i < 4; ++i) {
        #pragma unroll
        for (int r = 0; r < 4; ++r) {
            float mm = m_[i][r], ss = s_[i][r];
            #pragma unroll
            for (int off = 1; off < 16; off <<= 1) {
                float om = __shfl_xor(mm, off);
                float os = __shfl_xor(ss, off);
                float nm = fmaxf(mm, om);
                ss = ss * fexp2(mm - nm) + os * fexp2(om - nm);
                mm = nm;
            }
            if (l15 == 0) {
                int row = wy * 64 + i * 16 + quad * 4 + r;
                redM[wx][row] = mm;
                redS[wx][row] = ss;
            }
        }
    }
    __syncthreads();
    if (tid < BM) {
        float m0 = redM[0][tid], m1 = redM[1][tid];
        float s0 = redS[0][tid], s1 = redS[1][tid];
        float M = fmaxf(m0, m1);
        float S = s0 * fexp2(m0 - M) + s1 * fexp2(m1 - M);
        pm[(size_t)(b0 + tid) * NSPLIT + chunk] = M;
        ps[(size_t)(b0 + tid) * NSPLIT + chunk] = S;
    }
}

// ---- combine partial (m,s) across N-chunks ----
__global__ void kde_combine(const float* __restrict__ pm, const float* __restrict__ ps,
                            const float* __restrict__ rc, const float* __restrict__ lsew,
                            float* __restrict__ out)
{
    int b = blockIdx.x * blockDim.x + threadIdx.x;
    if (b >= B_ROWS) return;
    float M = -INFINITY;
    #pragma unroll
    for (int c = 0; c < NSPLIT; ++c) M = fmaxf(M, pm[(size_t)b * NSPLIT + c]);
    float S = 0.f;
    #pragma unroll
    for (int c = 0; c < NSPLIT; ++c)
        S += ps[(size_t)b * NSPLIT + c] * fexp2(pm[(size_t)b * NSPLIT + c] - M);
    out[b] = (M + log2f(S)) * LN2_F + rc[b] - lsew[0];
}

extern "C" void kernel_launch(void* const* d_in, const int* in_sizes, int n_in,
                              void* d_out, int out_size, void* d_ws, size_t ws_size,
                              hipStream_t stream)
{
    const float* x = (const float*)d_in[0];
    const float* X = (const float*)d_in[1];
    const float* W = (const float*)d_in[2];
    float* out = (float*)d_out;

    char* ws = (char*)d_ws;
    size_t off = 0;
    __bf16* xb = (__bf16*)(ws + off); off += (size_t)B_ROWS * D_DIM * 2;   // 4 MB
    __bf16* Xb = (__bf16*)(ws + off); off += (size_t)N_PTS  * D_DIM * 2;   // 8 MB
    float* rc   = (float*)(ws + off); off += (size_t)B_ROWS * 4;
    float* c2   = (float*)(ws + off); off += (size_t)N_PTS * 4;
    float* lsew = (float*)(ws + off); off += 256;
    float* pm   = (float*)(ws + off); off += (size_t)B_ROWS * NSPLIT * 4;
    float* ps   = (float*)(ws + off); off += (size_t)B_ROWS * NSPLIT * 4;

    prep_x_kernel<<<B_ROWS, 256, 0, stream>>>(x, xb, rc);
    prep_X_kernel<<<N_PTS, 256, 0, stream>>>(X, W, Xb, c2);
    prep_w_kernel<<<1, 256, 0, stream>>>(W, lsew);
    kde_gemm<<<dim3(B_ROWS / BM, NSPLIT), 256, 0, stream>>>(xb, Xb, c2, pm, ps);
    kde_combine<<<B_ROWS / 256, 256, 0, stream>>>(pm, ps, rc, lsew, out);
}